// Round 2
// baseline (303.214 us; speedup 1.0000x reference)
//
#include <hip/hip_runtime.h>

// Problem shapes (fixed by setup_inputs)
namespace {
constexpr int B  = 8;
constexpr int N  = 100;
constexpr int C  = 256;
constexpr int H  = 160;
constexpr int W  = 160;
constexpr int NC = 80;     // NUM_CLASSES
constexpr int T  = 1024;   // threads/block = 16 waves
constexpr int NW = 16;     // waves/block
constexpr int RPW = H / NW;// 10 rows per wave per plane
constexpr int PC  = 4;     // channel planes per block (same b)
constexpr int NB  = C / PC;// 64 c-chunks -> grid = B*NB = 512 = 2 blocks/CU
constexpr int TR  = PC * RPW; // 40 rows per wave total
constexpr int SCR = 164;   // per-buffer prefix scratch stride (floats)
constexpr int HW  = H * W;
}

// image_h / image_w arrive as 1-element arrays of unknown dtype (python
// scalar). Read as int32; if implausible, reinterpret the bits as float32.
__device__ inline float read_dim(const int* p) {
    int i = *p;
    if (i >= 1 && i <= (1 << 26)) return (float)i;
    return __int_as_float(i);
}

// One step of the wave64 inclusive scan, VALU-only (no LDS):
// s += dpp_shifted(s); invalid-source lanes contribute old=0.
#define DPP_ADD(s, ctrl, rmask)                                              \
    s += __int_as_float(__builtin_amdgcn_update_dpp(                          \
        0, __float_as_int(s), (ctrl), (rmask), 0xf, false))

extern "C" __global__ void __launch_bounds__(T)
vpe_kernel(const float* __restrict__ features,  // [B,C,H,W]
           const float* __restrict__ boxes,     // [B,N,4]
           const int*   __restrict__ gt,        // [B,N]
           const int*   __restrict__ neg_y,     // [B,NC]
           const int*   __restrict__ neg_x,     // [B,NC]
           const int*   __restrict__ imh_p,     // scalar
           const int*   __restrict__ imw_p,     // scalar
           float*       __restrict__ out)       // [B,NC,C]
{
    // One block per (b, 4-channel chunk). Box setup once per block (same b
    // for all 4 planes); per-lane box registers persist across planes. The
    // 40-row main loop (4 planes x 10 rows/wave) runs with NO __syncthreads:
    // per-plane cls_sum buffers make the plane switch a register flush (2 LDS
    // atomics). DPP scan for row prefixes, double-buffered per-wave scratch,
    // depth-3 row prefetch that spans plane boundaries.
    __shared__ float rs[NW * 2 * SCR];   // ~21 KB prefix scratch
    __shared__ float cls_sum[PC][NC];
    __shared__ int   cls_cnt[NC];
    __shared__ int   bx1m[N], bx2m[N], by1[N], by2[N], bcls[N];
    __shared__ float bwgt[N];

    const int tid  = threadIdx.x;
    const int wave = tid >> 6, lane = tid & 63;
    const int b    = blockIdx.x / NB;
    const int c0   = (blockIdx.x % NB) * PC;
    const float* plane0 = features + (size_t)(b * C + c0) * HW;

    if (tid < PC * NC) ((float*)cls_sum)[tid] = 0.f;
    if (tid < NC) cls_cnt[tid] = 0;
    __syncthreads();

    // Box setup (uniform per b; once per block).
    if (tid < N) {
        float imw = read_dim(imw_p), imh = read_dim(imh_p);
        float sx = (float)W / imw, sy = (float)H / imh;
        const float* bp = boxes + (size_t)(b * N + tid) * 4;
        int x1 = (int)fminf(fmaxf(floorf(bp[0] * sx), 0.f), (float)W);
        int y1 = (int)fminf(fmaxf(floorf(bp[1] * sy), 0.f), (float)H);
        int x2 = (int)fminf(fmaxf(floorf(bp[2] * sx), 0.f), (float)W);
        int y2 = (int)fminf(fmaxf(floorf(bp[3] * sy), 0.f), (float)H);
        bool valid = (x2 > x1) && (y2 > y1);
        bx1m[tid] = x1 - 1; bx2m[tid] = x2 - 1;
        by1[tid] = y1; by2[tid] = y2;
        int cls = gt[b * N + tid];
        bcls[tid] = valid ? cls : -1;
        bwgt[tid] = 1.f / (float)max((x2 - x1) * (y2 - y1), 1);
        if (valid) atomicAdd(&cls_cnt[cls], 1);
    }
    __syncthreads();
    // Fold the class-count divisor into the per-box weight.
    if (tid < N && bcls[tid] >= 0)
        bwgt[tid] /= (float)max(cls_cnt[bcls[tid]], 1);
    __syncthreads();

    // Per-lane box registers: lane owns boxes nA=lane and nB=lane+64.
    // Same for all PC planes (same b).
    float* buf0 = &rs[(wave * 2 + 0) * SCR];
    float* buf1 = &rs[(wave * 2 + 1) * SCR];
    const int nA = lane, nB = lane + 64;
    const int clsA = bcls[nA];
    const int y1A = by1[nA], y2A = by2[nA], x1A = bx1m[nA], x2A = bx2m[nA];
    const float wA = bwgt[nA];
    int clsB = -1, y1B = 0, y2B = 0, x1B = 0, x2B = 0; float wB = 0.f;
    if (nB < N) {
        clsB = bcls[nB]; y1B = by1[nB]; y2B = by2[nB];
        x1B = bx1m[nB]; x2B = bx2m[nB]; wB = bwgt[nB];
    }

    float accA = 0.f, accB = 0.f;
    const bool ldr = (lane < W / 4);   // 40 loader lanes cover one 640B row
    const float4 z4 = make_float4(0.f, 0.f, 0.f, 0.f);

    // Flattened row index ri in [0, TR): plane pi = ri/RPW, row-in-plane
    // r = ri%RPW, y = wave + r*16. Prefetch crosses plane boundaries.
    auto ld = [&](int ri) -> float4 {
        if (!ldr || ri >= TR) return z4;
        int pi = ri / RPW;
        int y  = wave + ((ri - pi * RPW) << 4);
        return ((const float4*)(plane0 + (size_t)pi * HW + (size_t)y * W))[lane];
    };

    // Depth-3 prefetch pipeline.
    float4 v0 = ld(0), v1 = ld(1), v2 = ld(2);

    for (int ri = 0; ri < TR; ++ri) {
        float4 v3 = ld(ri + 3);
        const int pi = ri / RPW;
        const int r  = ri - pi * RPW;
        const int y  = wave + (r << 4);

        // Lane-local partial prefixes (independent of the scan chain).
        float q1 = v0.x, q2 = q1 + v0.y, q3 = q2 + v0.z, t = q3 + v0.w;

        // Wave64 inclusive scan of lane totals — 6 dependent VALU adds.
        float s = t;
        DPP_ADD(s, 0x111, 0xf);   // row_shr:1
        DPP_ADD(s, 0x112, 0xf);   // row_shr:2
        DPP_ADD(s, 0x114, 0xf);   // row_shr:4
        DPP_ADD(s, 0x118, 0xf);   // row_shr:8
        DPP_ADD(s, 0x142, 0xa);   // row_bcast:15 -> rows 1,3
        DPP_ADD(s, 0x143, 0xc);   // row_bcast:31 -> rows 2,3
        float e = s - t;          // exclusive across lanes

        float* cb = (ri & 1) ? buf1 : buf0;
        if (ldr)
            ((float4*)cb)[lane] = make_float4(e + q1, e + q2, e + q3, s);
        __builtin_amdgcn_wave_barrier();   // write visible before the gathers

        // Private per-lane box accumulation (no atomics in steady state).
        if (clsA >= 0 && y >= y1A && y < y2A) {
            float hi = cb[x2A];
            float lo = (x1A >= 0) ? cb[x1A] : 0.f;
            accA += hi - lo;
        }
        if (clsB >= 0 && y >= y1B && y < y2B) {
            float hi = cb[x2B];
            float lo = (x1B >= 0) ? cb[x1B] : 0.f;
            accB += hi - lo;
        }
        // No trailing barrier: ri+1 writes the other buffer; ri+2's
        // overwrite of cb is fenced by ri+1's wave_barrier.

        // Plane finished for this wave: flush accumulators (no block sync —
        // per-plane cls_sum buffer, read only after the final syncthreads).
        if (r == RPW - 1) {
            if (clsA >= 0) atomicAdd(&cls_sum[pi][clsA], accA * wA);
            if (clsB >= 0) atomicAdd(&cls_sum[pi][clsB], accB * wB);
            accA = 0.f; accB = 0.f;
        }
        v0 = v1; v1 = v2; v2 = v3;
    }
    __syncthreads();

    // Epilogue: mean (already /cnt via bwgt) or negative-pixel fallback,
    // for all PC planes at once.
    if (tid < PC * NC) {
        const int pi = tid / NC, cls = tid - pi * NC;
        const int cnt = cls_cnt[cls];
        const float* pl = plane0 + (size_t)pi * HW;
        float o = (cnt > 0) ? cls_sum[pi][cls]
                            : pl[neg_y[b * NC + cls] * W + neg_x[b * NC + cls]];
        out[((size_t)b * NC + cls) * C + (c0 + pi)] = o;
    }
}

extern "C" void kernel_launch(void* const* d_in, const int* in_sizes, int n_in,
                              void* d_out, int out_size, void* d_ws, size_t ws_size,
                              hipStream_t stream) {
    (void)in_sizes; (void)n_in; (void)d_ws; (void)ws_size; (void)out_size;
    vpe_kernel<<<dim3(B * NB), dim3(T), 0, stream>>>(
        (const float*)d_in[0],   // features
        (const float*)d_in[1],   // boxes
        (const int*)d_in[2],     // gt_classes
        (const int*)d_in[3],     // neg_y
        (const int*)d_in[4],     // neg_x
        (const int*)d_in[5],     // image_h
        (const int*)d_in[6],     // image_w
        (float*)d_out);
}